// Round 6
// baseline (3293.155 us; speedup 1.0000x reference)
//
#include <hip/hip_runtime.h>

#define B_ 4
#define N_ 40000
#define E_ 240000

typedef unsigned short u16;
typedef unsigned int u32;
typedef __attribute__((ext_vector_type(8))) short bf16x8;
typedef __attribute__((ext_vector_type(4))) float f32x4;

__device__ __forceinline__ float b2f(u16 h) {
    u32 u = ((u32)h) << 16;
    return __uint_as_float(u);
}
__device__ __forceinline__ u16 f2b(float f) {
    u32 u = __float_as_uint(f);
    u32 r = (u + 0x7fffu + ((u >> 16) & 1u)) >> 16;
    return (u16)r;
}
__device__ __forceinline__ float4 f4_zero() { return make_float4(0.f, 0.f, 0.f, 0.f); }

// ---------------- first linear: x = x_in @ w_first + b_first (bf16 out) ----------------
__global__ __launch_bounds__(256) void first_linear_kern(
    const float* __restrict__ x_in, const float* __restrict__ w,
    const float* __restrict__ bias, u16* __restrict__ xout, int M)
{
    __shared__ float sw[6 * 128];
    __shared__ float sb[128];
    int t = threadIdx.x;
    for (int i = t; i < 768; i += 256) sw[i] = w[i];
    if (t < 128) sb[t] = bias[t];
    __syncthreads();
    int idx = blockIdx.x * 256 + t;
    int row = idx >> 7;
    int c = idx & 127;
    if (row >= M) return;
    const float* xr = x_in + (size_t)row * 6;
    float acc = sb[c];
#pragma unroll
    for (int j = 0; j < 6; j++) acc += xr[j] * sw[j * 128 + c];
    xout[(size_t)row * 128 + c] = f2b(acc);
}

// ------------- weight pack: dst[n][k] = bf16(src[k][n]), per block i = blockIdx.z -------------
__global__ __launch_bounds__(256) void pack_w_kern(
    const float* __restrict__ src, u16* __restrict__ dst, int K)
{
    int i = blockIdx.z;
    src += (size_t)i * K * 128;
    dst += (size_t)i * K * 128;
    int idx = blockIdx.x * 256 + threadIdx.x;  // = n*K + k
    int n = idx / K;
    int k = idx % K;
    dst[idx] = f2b(src[(size_t)k * 128 + n]);
}

// ------------- rotation weight pack: WR1[n][k256] = [Are; -Aim]^T, WR2 = [Are; Aim]^T -------------
__global__ __launch_bounds__(256) void pack_rot_kern(
    const float* __restrict__ Are, const float* __restrict__ Aim,
    u16* __restrict__ WR1, u16* __restrict__ WR2)
{
    int i = blockIdx.z;
    const float* are = Are + (size_t)i * 16384;
    const float* aim = Aim + (size_t)i * 16384;
    int idx = blockIdx.x * 256 + threadIdx.x;  // 0..32767 = n*256 + k
    int n = idx >> 8;
    int k = idx & 255;
    float v1, v2;
    if (k < 128) { float a = are[(size_t)k * 128 + n]; v1 = a; v2 = a; }
    else         { float a = aim[(size_t)(k - 128) * 128 + n]; v1 = -a; v2 = a; }
    WR1[(size_t)i * 32768 + idx] = f2b(v1);
    WR2[(size_t)i * 32768 + idx] = f2b(v2);
}

// ------------- CSR build: histogram -> 3-stage parallel scan -> scatter -------------
__global__ __launch_bounds__(256) void hist_kern(const int* __restrict__ rows, int* count)
{
    int e = blockIdx.x * 256 + threadIdx.x;
    if (e < E_) atomicAdd(&count[rows[e]], 1);
}

// per-block exclusive scan of counts; writes locex[i] and block sums bsum[blk]
__global__ __launch_bounds__(256) void scan_local_kern(
    const int* __restrict__ count, int* __restrict__ locex, int* __restrict__ bsum)
{
    __shared__ int buf[256];
    int t = threadIdx.x;
    int i = blockIdx.x * 256 + t;
    int v = (i < N_) ? count[i] : 0;
    buf[t] = v;
    __syncthreads();
#pragma unroll
    for (int off = 1; off < 256; off <<= 1) {
        int add = (t >= off) ? buf[t - off] : 0;
        __syncthreads();
        buf[t] += add;
        __syncthreads();
    }
    if (i < N_) locex[i] = buf[t] - v;
    if (t == 255) bsum[blockIdx.x] = buf[255];
}

// single block: exclusive scan of bsum[0..nb-1] -> btop
__global__ __launch_bounds__(256) void scan_top_kern(
    const int* __restrict__ bsum, int* __restrict__ btop, int nb)
{
    __shared__ int buf[256];
    int t = threadIdx.x;
    int v = (t < nb) ? bsum[t] : 0;
    buf[t] = v;
    __syncthreads();
#pragma unroll
    for (int off = 1; off < 256; off <<= 1) {
        int add = (t >= off) ? buf[t - off] : 0;
        __syncthreads();
        buf[t] += add;
        __syncthreads();
    }
    if (t < nb) btop[t] = buf[t] - v;
}

// rowptr[i] = nextp[i] = locex[i] + btop[blk]; rowptr[N] = E
__global__ __launch_bounds__(256) void scan_fix_kern(
    const int* __restrict__ locex, const int* __restrict__ btop,
    int* __restrict__ rowptr, int* __restrict__ nextp)
{
    int t = threadIdx.x;
    int i = blockIdx.x * 256 + t;
    if (i < N_) {
        int v = locex[i] + btop[blockIdx.x];
        rowptr[i] = v;
        nextp[i] = v;
    }
    if (i == 0) rowptr[N_] = E_;
}

__global__ __launch_bounds__(256) void scatter_kern(
    const int* __restrict__ rows, const int* __restrict__ cols,
    const float* __restrict__ gvx, const float* __restrict__ gvy,
    int* nextp, int* __restrict__ scols,
    float* __restrict__ svx, float* __restrict__ svy)
{
    int e = blockIdx.x * 256 + threadIdx.x;
    if (e >= E_) return;
    int r = rows[e];
    int pos = atomicAdd(&nextp[r], 1);
    scols[pos] = cols[e];
#pragma unroll
    for (int b = 0; b < B_; b++) {
        svx[(size_t)b * E_ + pos] = gvx[(size_t)b * E_ + e];
        svy[(size_t)b * E_ + pos] = gvy[(size_t)b * E_ + e];
    }
}

// ------------- MFMA spectral projection stage 1: partial[c][k] = sum_n x[n,c]*mass[n]*ev[n,k] -------------
// grid (64, B); 64 partial slabs per batch, slab layout [c=128][k=128] f32.
// Each wave owns a 32-c stripe (mw = wv*32) across ALL 128 k: acc[2][8].
__global__ __launch_bounds__(256) void spec1_mfma_kern(
    const u16* __restrict__ x, const float* __restrict__ mass,
    const float* __restrict__ evecs, float* __restrict__ partials)
{
    __shared__ u16 sXt[128][40];   // [c][n-chunk] transposed, 80B rows (16B aligned)
    __shared__ u16 sEVt[128][40];  // [k][n-chunk]
    int b = blockIdx.y;
    int pb = blockIdx.x;
    const u16* xb = x + (size_t)b * N_ * 128;
    const float* mb = mass + (size_t)b * N_;
    const float* eb = evecs + (size_t)b * N_ * 128;

    int t = threadIdx.x;
    int wv = t >> 6;
    int lane = t & 63;
    int quad = lane >> 4;
    int r16 = lane & 15;
    int mw = wv * 32;          // c stripe per wave: 0,32,64,96

    f32x4 acc[2][8];
#pragma unroll
    for (int i = 0; i < 2; i++)
#pragma unroll
        for (int j = 0; j < 8; j++) acc[i][j] = (f32x4){0.f, 0.f, 0.f, 0.f};

#pragma unroll 1
    for (int ch = pb; ch < N_ / 32; ch += 64) {
        int n0 = ch * 32;
        __syncthreads();
        // stage transposed: 32 n-rows x 128 cols each for x*mass and evecs
#pragma unroll
        for (int p = 0; p < 4; p++) {
            int idx = p * 256 + t;     // 0..1023
            int nn = idx >> 5;         // 32 n
            int c4 = (idx & 31) * 4;   // 128 cols in 4-chunks
            float mm = mb[n0 + nn];
            ushort4 xh = *(const ushort4*)(xb + (size_t)(n0 + nn) * 128 + c4);
            sXt[c4 + 0][nn] = f2b(b2f(xh.x) * mm);
            sXt[c4 + 1][nn] = f2b(b2f(xh.y) * mm);
            sXt[c4 + 2][nn] = f2b(b2f(xh.z) * mm);
            sXt[c4 + 3][nn] = f2b(b2f(xh.w) * mm);
            float4 ev = *(const float4*)(eb + (size_t)(n0 + nn) * 128 + c4);
            sEVt[c4 + 0][nn] = f2b(ev.x);
            sEVt[c4 + 1][nn] = f2b(ev.y);
            sEVt[c4 + 2][nn] = f2b(ev.z);
            sEVt[c4 + 3][nn] = f2b(ev.w);
        }
        __syncthreads();
        int ko = quad * 8;
        bf16x8 a0 = *(const bf16x8*)&sXt[mw + r16][ko];
        bf16x8 a1 = *(const bf16x8*)&sXt[mw + 16 + r16][ko];
#pragma unroll
        for (int j = 0; j < 8; j++) {
            bf16x8 bj = *(const bf16x8*)&sEVt[16 * j + r16][ko];
            acc[0][j] = __builtin_amdgcn_mfma_f32_16x16x32_bf16(a0, bj, acc[0][j], 0, 0, 0);
            acc[1][j] = __builtin_amdgcn_mfma_f32_16x16x32_bf16(a1, bj, acc[1][j], 0, 0, 0);
        }
    }

    float* slab = partials + ((size_t)b * 64 + pb) * 16384;
#pragma unroll
    for (int j = 0; j < 8; j++) {
        int col = 16 * j + r16;         // k
#pragma unroll
        for (int mt = 0; mt < 2; mt++) {
#pragma unroll
            for (int reg = 0; reg < 4; reg++) {
                int row = mw + mt * 16 + quad * 4 + reg;  // c
                slab[(size_t)row * 128 + col] = acc[mt][j][reg];
            }
        }
    }
}

// ------------- stage 2 + coefficients: ys_t[b][c][k] = exp(-evals[k]*dt[c]) * sum_pb partial[c][k] -------------
__global__ __launch_bounds__(128) void spec_stage2_coef_kern(
    const float* __restrict__ partials, const float* __restrict__ evals,
    const float* __restrict__ dt, u16* __restrict__ ys_t)
{
    int b = blockIdx.x >> 7;
    int c = blockIdx.x & 127;
    int k = threadIdx.x;
    const float* p = partials + (size_t)b * 64 * 16384 + (size_t)c * 128 + k;
    float s = 0.f;
#pragma unroll 8
    for (int pb = 0; pb < 64; pb++) s += p[(size_t)pb * 16384];
    float co = expf(-evals[b * 128 + k] * dt[c]);
    ys_t[((size_t)b * 128 + c) * 128 + k] = f2b(s * co);
}

// ------------- MFMA GEMM: out[m,0:128] = act(A[m,:KK] @ W + bias + resid), bf16 out -------------
template <int KK, bool CONCAT3, bool RELU, bool RESID, bool HASBIAS, bool AF32>
__global__ __launch_bounds__(256) void mgemm_kern(
    const void* __restrict__ A0v, const void* __restrict__ A1v, const void* __restrict__ A2v,
    const u16* __restrict__ Wp, const float* __restrict__ bias,
    const u16* __restrict__ resid, u16* __restrict__ outp,
    size_t aBatch, size_t wBatch, size_t oBatch)
{
    __shared__ u16 sA[64][72];    // padded: 144B row stride
    __shared__ u16 sB[128][72];
    int z = blockIdx.z;
    const u16* Wb = Wp + wBatch * (size_t)z;
    size_t aOff = aBatch * (size_t)z;
    size_t oOff = oBatch * (size_t)z;

    int t = threadIdx.x;
    int m0 = blockIdx.x * 64;
    int wv = t >> 6;
    int lane = t & 63;
    int quad = lane >> 4;
    int r16 = lane & 15;
    int mw = (wv & 1) * 32;
    int nw = (wv >> 1) * 64;

    f32x4 acc[2][4];
#pragma unroll
    for (int i = 0; i < 2; i++)
#pragma unroll
        for (int j = 0; j < 4; j++) acc[i][j] = (f32x4){0.f, 0.f, 0.f, 0.f};

#pragma unroll 1
    for (int kt = 0; kt < KK / 64; kt++) {
        int kbase = kt * 64;
        const void* Ap;
        if (CONCAT3) Ap = (kbase < 128) ? A0v : (kbase < 256) ? A1v : A2v;
        else Ap = A0v;
        int kloc = CONCAT3 ? (kbase & 127) : kbase;

        __syncthreads();
        if (AF32) {
            const float* Af = (const float*)Ap + aOff;
#pragma unroll
            for (int p = 0; p < 4; p++) {
                int idx = p * 256 + t;       // 0..1023
                int row = idx >> 4;          // 64 rows
                int seg = idx & 15;          // 16 segs of 4 floats
                float4 v = *(const float4*)(Af + (size_t)(m0 + row) * 128 + kloc + seg * 4);
                ushort4 h;
                h.x = f2b(v.x); h.y = f2b(v.y); h.z = f2b(v.z); h.w = f2b(v.w);
                *(ushort4*)&sA[row][seg * 4] = h;
            }
        } else {
            const u16* Ah = (const u16*)Ap + aOff;
#pragma unroll
            for (int p = 0; p < 2; p++) {
                int idx = p * 256 + t;       // 0..511
                int row = idx >> 3;          // 64 rows
                int seg = idx & 7;           // 8 segs of 8 u16
                *(uint4*)&sA[row][seg * 8] =
                    *(const uint4*)(Ah + (size_t)(m0 + row) * 128 + kloc + seg * 8);
            }
        }
        {
#pragma unroll
            for (int p = 0; p < 4; p++) {
                int idx = p * 256 + t;       // 0..1023
                int n = idx >> 3;            // 128 n
                int seg = idx & 7;           // 8 segs of 8 u16
                *(uint4*)&sB[n][seg * 8] =
                    *(const uint4*)(Wb + (size_t)n * KK + kbase + seg * 8);
            }
        }
        __syncthreads();

#pragma unroll
        for (int ks = 0; ks < 2; ks++) {
            int ko = ks * 32 + quad * 8;
            bf16x8 a0 = *(const bf16x8*)&sA[mw + r16][ko];
            bf16x8 a1 = *(const bf16x8*)&sA[mw + 16 + r16][ko];
            bf16x8 b0 = *(const bf16x8*)&sB[nw + r16][ko];
            bf16x8 b1 = *(const bf16x8*)&sB[nw + 16 + r16][ko];
            bf16x8 b2 = *(const bf16x8*)&sB[nw + 32 + r16][ko];
            bf16x8 b3 = *(const bf16x8*)&sB[nw + 48 + r16][ko];
            acc[0][0] = __builtin_amdgcn_mfma_f32_16x16x32_bf16(a0, b0, acc[0][0], 0, 0, 0);
            acc[0][1] = __builtin_amdgcn_mfma_f32_16x16x32_bf16(a0, b1, acc[0][1], 0, 0, 0);
            acc[0][2] = __builtin_amdgcn_mfma_f32_16x16x32_bf16(a0, b2, acc[0][2], 0, 0, 0);
            acc[0][3] = __builtin_amdgcn_mfma_f32_16x16x32_bf16(a0, b3, acc[0][3], 0, 0, 0);
            acc[1][0] = __builtin_amdgcn_mfma_f32_16x16x32_bf16(a1, b0, acc[1][0], 0, 0, 0);
            acc[1][1] = __builtin_amdgcn_mfma_f32_16x16x32_bf16(a1, b1, acc[1][1], 0, 0, 0);
            acc[1][2] = __builtin_amdgcn_mfma_f32_16x16x32_bf16(a1, b2, acc[1][2], 0, 0, 0);
            acc[1][3] = __builtin_amdgcn_mfma_f32_16x16x32_bf16(a1, b3, acc[1][3], 0, 0, 0);
        }
    }

    // epilogue: D[row=quad*4+reg][col=r16] per 16x16 tile
#pragma unroll
    for (int nt = 0; nt < 4; nt++) {
        int col = nw + nt * 16 + r16;
        float bv = HASBIAS ? bias[col] : 0.f;
#pragma unroll
        for (int mt = 0; mt < 2; mt++) {
#pragma unroll
            for (int reg = 0; reg < 4; reg++) {
                int row = m0 + mw + mt * 16 + quad * 4 + reg;
                float v = acc[mt][nt][reg] + bv;
                if (RESID) v += b2f(resid[(size_t)row * 128 + col]);
                if (RELU) v = fmaxf(v, 0.f);
                outp[oOff + (size_t)row * 128 + col] = f2b(v);
            }
        }
    }
}

// ------------- fused CSR spMM + MFMA rotation + tanh; grid (N/64, B) -------------
__global__ __launch_bounds__(256) void spmm_rotate_kern(
    const int* __restrict__ rowptr, const int* __restrict__ scols,
    const float* __restrict__ svx, const float* __restrict__ svy,
    const u16* __restrict__ xd, const u16* __restrict__ WR1, const u16* __restrict__ WR2,
    u16* __restrict__ gf)
{
    __shared__ u16 sGX[64][136];
    __shared__ u16 sGY[64][136];
    __shared__ u16 sB1[128][72];
    __shared__ u16 sB2[128][72];

    int b = blockIdx.y;
    const u16* xd_b = xd + (size_t)b * N_ * 128;
    const float* svx_b = svx + (size_t)b * E_;
    const float* svy_b = svy + (size_t)b * E_;
    u16* gf_b = gf + (size_t)b * N_ * 128;

    int t = threadIdx.x;
    int m0 = blockIdx.x * 64;
    int wv = t >> 6;
    int lane = t & 63;
    int quad = lane >> 4;
    int r16 = lane & 15;
    int mw = (wv & 1) * 32;
    int nw = (wv >> 1) * 64;

    // --- phase 1: CSR gather -> sGX/sGY (bf16) ---
    {
        int cg = t & 127;
        int half = t >> 7;
#pragma unroll 1
        for (int p = 0; p < 32; p++) {
            int rloc = p * 2 + half;
            int r = m0 + rloc;
            int beg = rowptr[r], end = rowptr[r + 1];
            float ax = 0.f, ay = 0.f;
            for (int j = beg; j < end; j++) {
                int col = scols[j];
                float xv = b2f(xd_b[(size_t)col * 128 + cg]);
                ax += svx_b[j] * xv;
                ay += svy_b[j] * xv;
            }
            sGX[rloc][cg] = f2b(ax);
            sGY[rloc][cg] = f2b(ay);
        }
    }

    f32x4 accRe[2][4], accIm[2][4];
#pragma unroll
    for (int i = 0; i < 2; i++)
#pragma unroll
        for (int j = 0; j < 4; j++) {
            accRe[i][j] = (f32x4){0.f, 0.f, 0.f, 0.f};
            accIm[i][j] = (f32x4){0.f, 0.f, 0.f, 0.f};
        }

    // --- phase 2: rotation GEMM (K=256 via concat trick) ---
#pragma unroll 1
    for (int c = 0; c < 4; c++) {
        __syncthreads();
#pragma unroll
        for (int p = 0; p < 4; p++) {
            int idx = p * 256 + t;
            int n = idx >> 3;
            int seg = idx & 7;
            *(uint4*)&sB1[n][seg * 8] = *(const uint4*)(WR1 + (size_t)n * 256 + c * 64 + seg * 8);
            *(uint4*)&sB2[n][seg * 8] = *(const uint4*)(WR2 + (size_t)n * 256 + c * 64 + seg * 8);
        }
        __syncthreads();

        const u16 (*sRe)[136] = (c < 2) ? sGX : sGY;
        const u16 (*sIm)[136] = (c < 2) ? sGY : sGX;
        int kob = (c & 1) * 64;
#pragma unroll
        for (int ks = 0; ks < 2; ks++) {
            int ko = kob + ks * 32 + quad * 8;
            int kb = ks * 32 + quad * 8;
            bf16x8 aRe0 = *(const bf16x8*)&sRe[mw + r16][ko];
            bf16x8 aRe1 = *(const bf16x8*)&sRe[mw + 16 + r16][ko];
            bf16x8 aIm0 = *(const bf16x8*)&sIm[mw + r16][ko];
            bf16x8 aIm1 = *(const bf16x8*)&sIm[mw + 16 + r16][ko];
#pragma unroll
            for (int j = 0; j < 4; j++) {
                bf16x8 b1 = *(const bf16x8*)&sB1[nw + 16 * j + r16][kb];
                bf16x8 b2 = *(const bf16x8*)&sB2[nw + 16 * j + r16][kb];
                accRe[0][j] = __builtin_amdgcn_mfma_f32_16x16x32_bf16(aRe0, b1, accRe[0][j], 0, 0, 0);
                accRe[1][j] = __builtin_amdgcn_mfma_f32_16x16x32_bf16(aRe1, b1, accRe[1][j], 0, 0, 0);
                accIm[0][j] = __builtin_amdgcn_mfma_f32_16x16x32_bf16(aIm0, b2, accIm[0][j], 0, 0, 0);
                accIm[1][j] = __builtin_amdgcn_mfma_f32_16x16x32_bf16(aIm1, b2, accIm[1][j], 0, 0, 0);
            }
        }
    }

    // --- phase 3: gf = tanh(gX*Breal + gY*Bimag) ---
#pragma unroll
    for (int nt = 0; nt < 4; nt++) {
        int col = nw + nt * 16 + r16;
#pragma unroll
        for (int mt = 0; mt < 2; mt++) {
#pragma unroll
            for (int reg = 0; reg < 4; reg++) {
                int rloc = mw + mt * 16 + quad * 4 + reg;
                float gx = b2f(sGX[rloc][col]);
                float gy = b2f(sGY[rloc][col]);
                float v = tanhf(gx * accRe[mt][nt][reg] + gy * accIm[mt][nt][reg]);
                gf_b[(size_t)(m0 + rloc) * 128 + col] = f2b(v);
            }
        }
    }
}

// ------------- last linear: out[m,0:3] = x[m,:] @ w_last + b_last -------------
__global__ __launch_bounds__(256) void last_linear_kern(
    const u16* __restrict__ x, const float* __restrict__ w,
    const float* __restrict__ bias, float* __restrict__ outp, int M)
{
    __shared__ float sw[128 * 3];
    int t = threadIdx.x;
    for (int i = t; i < 384; i += 256) sw[i] = w[i];
    __syncthreads();
    int wave = t >> 6;
    int lane = t & 63;
    int row = blockIdx.x * 4 + wave;
    if (row >= M) return;
    const u16* xr = x + (size_t)row * 128;
    float p0 = 0.f, p1 = 0.f, p2 = 0.f;
#pragma unroll
    for (int h = 0; h < 2; h++) {
        int c = lane + h * 64;
        float xv = b2f(xr[c]);
        p0 += xv * sw[c * 3 + 0];
        p1 += xv * sw[c * 3 + 1];
        p2 += xv * sw[c * 3 + 2];
    }
#pragma unroll
    for (int off = 32; off > 0; off >>= 1) {
        p0 += __shfl_xor(p0, off);
        p1 += __shfl_xor(p1, off);
        p2 += __shfl_xor(p2, off);
    }
    if (lane == 0) {
        float* o = outp + (size_t)row * 3;
        o[0] = p0 + bias[0];
        o[1] = p1 + bias[1];
        o[2] = p2 + bias[2];
    }
}

extern "C" void kernel_launch(void* const* d_in, const int* in_sizes, int n_in,
                              void* d_out, int out_size, void* d_ws, size_t ws_size,
                              hipStream_t stream)
{
    const float* x_in    = (const float*)d_in[0];
    const float* mass    = (const float*)d_in[1];
    const float* evals   = (const float*)d_in[2];
    const float* evecs   = (const float*)d_in[3];
    const int*   rows    = (const int*)  d_in[4];
    const int*   cols    = (const int*)  d_in[5];
    const float* gvx     = (const float*)d_in[6];
    const float* gvy     = (const float*)d_in[7];
    const float* w_first = (const float*)d_in[8];
    const float* b_first = (const float*)d_in[9];
    const float* dtimes  = (const float*)d_in[10];
    const float* A_re    = (const float*)d_in[11];
    const float* A_im    = (const float*)d_in[12];
    const float* w0      = (const float*)d_in[13];
    const float* b0      = (const float*)d_in[14];
    const float* w1      = (const float*)d_in[15];
    const float* b1      = (const float*)d_in[16];
    const float* w2      = (const float*)d_in[17];
    const float* b2      = (const float*)d_in[18];
    const float* w_last  = (const float*)d_in[19];
    const float* b_last  = (const float*)d_in[20];
    float* outp = (float*)d_out;

    const size_t SZ = (size_t)B_ * N_ * 128;   // 20,480,000 elements
    const size_t NZ = (size_t)N_ * 128;        //  5,120,000 elements

    // workspace layout (~174 MB)
    u16* P0 = (u16*)d_ws;                      // 41 MB  (x ping-pong)
    u16* P1 = P0 + SZ;                         // 41 MB  (xd ping-pong)
    u16* GF = P1 + SZ;                         // 41 MB  (grad_feat, then h2)
    float* SC = (float*)(GF + SZ);             // 41 MB  f32: spec partials (16.8MB) / h1
    u16* ys_t = (u16*)(SC + 8388608);          // 128 KB at +32MB inside SC
    u16* WP0 = (u16*)(SC + 2 * NZ);            // packed transposed bf16 weights
    u16* WP1 = WP0 + 4 * 49152;
    u16* WP2 = WP1 + 4 * 16384;
    u16* WR1 = WP2 + 4 * 16384;                // 4 x [128][256] rotation packs
    u16* WR2 = WR1 + 4 * 32768;
    int* rowptr = (int*)(WR2 + 4 * 32768);     // N+1 (padded to 40004)
    int* nextp  = rowptr + 40004;              // N (histogram counts, then cursors)
    int* locex  = nextp + N_;                  // N local exclusive scan
    int* bsum   = locex + N_;                  // 157 (pad 256)
    int* btop   = bsum + 256;                  // 157 (pad 256)
    int* scols  = btop + 256;                  // E sorted cols
    float* svx  = (float*)(scols + E_);        // [B][E] sorted vals
    float* svy  = svx + (size_t)B_ * E_;

    u16* x  = P0;
    u16* xd = P1;
    const int M = B_ * N_;                     // 160000
    const int NB = (N_ + 255) / 256;           // 157

    // --- CSR build (pattern shared across blocks & X/Y) ---
    hipMemsetAsync(nextp, 0, N_ * sizeof(int), stream);
    hist_kern<<<dim3((E_ + 255) / 256), 256, 0, stream>>>(rows, nextp);
    scan_local_kern<<<dim3(NB), 256, 0, stream>>>(nextp, locex, bsum);
    scan_top_kern<<<dim3(1), 256, 0, stream>>>(bsum, btop, NB);
    scan_fix_kern<<<dim3(NB), 256, 0, stream>>>(locex, btop, rowptr, nextp);
    scatter_kern<<<dim3((E_ + 255) / 256), 256, 0, stream>>>(
        rows, cols, gvx, gvy, nextp, scols, svx, svy);

    // --- weight packing (once per launch) ---
    pack_w_kern<<<dim3(192, 1, 4), 256, 0, stream>>>(w0, WP0, 384);
    pack_w_kern<<<dim3(64, 1, 4), 256, 0, stream>>>(w1, WP1, 128);
    pack_w_kern<<<dim3(64, 1, 4), 256, 0, stream>>>(w2, WP2, 128);
    pack_rot_kern<<<dim3(128, 1, 4), 256, 0, stream>>>(A_re, A_im, WR1, WR2);

    first_linear_kern<<<dim3(M * 128 / 256), 256, 0, stream>>>(x_in, w_first, b_first, x, M);

    for (int i = 0; i < 4; i++) {
        // --- spectral diffusion (MFMA stage1 -> stage2 -> MFMA expand) ---
        spec1_mfma_kern<<<dim3(64, B_), 256, 0, stream>>>(x, mass, evecs, SC);
        spec_stage2_coef_kern<<<dim3(B_ * 128), 128, 0, stream>>>(
            SC, evals, dtimes + (size_t)i * 128, ys_t);
        mgemm_kern<128, false, false, false, false, true>
            <<<dim3(N_ / 64, 1, B_), 256, 0, stream>>>(
            evecs, nullptr, nullptr, ys_t, nullptr, nullptr, xd,
            NZ, (size_t)128 * 128, NZ);
        // --- fused sparse gradients + rotation (all batches) ---
        spmm_rotate_kern<<<dim3(N_ / 64, B_), 256, 0, stream>>>(
            rowptr, scols, svx, svy, xd,
            WR1 + (size_t)i * 32768, WR2 + (size_t)i * 32768, GF);
        // --- MiniMLP + residual ---
        u16* h1 = (u16*)SC;
        mgemm_kern<384, true, true, false, true, false>
            <<<dim3(M / 64), 256, 0, stream>>>(
            x, xd, GF, WP0 + (size_t)i * 49152, b0 + (size_t)i * 128, nullptr, h1, 0, 0, 0);
        mgemm_kern<128, false, true, false, true, false>
            <<<dim3(M / 64), 256, 0, stream>>>(
            h1, nullptr, nullptr, WP1 + (size_t)i * 16384, b1 + (size_t)i * 128, nullptr, GF, 0, 0, 0);
        mgemm_kern<128, false, false, true, true, false>
            <<<dim3(M / 64), 256, 0, stream>>>(
            GF, nullptr, nullptr, WP2 + (size_t)i * 16384, b2 + (size_t)i * 128, x, xd, 0, 0, 0);
        u16* tmp = x; x = xd; xd = tmp;
    }

    last_linear_kern<<<dim3(M / 4), 256, 0, stream>>>(x, w_last, b_last, outp, M);
}